// Round 3
// baseline (88.301 us; speedup 1.0000x reference)
//
#include <hip/hip_runtime.h>

// y[n][r] = sum_c weights[weight_idx[n]][r][c] * values[input_idx[n]][c]
// N=2M, M=2M, U=1024, R=C=8. All f32.
// Latency-bound random gather: 4 neurons/thread, batched independent loads
// for memory-level parallelism. Grid-stride assignment keeps every
// load/store instruction lane-coalesced.
// Native clang vector type (not HIP_vector_type) so nontemporal builtins accept it.
typedef float f32x4 __attribute__((ext_vector_type(4)));

#define NPT 4  // neurons per thread

__global__ __launch_bounds__(256) void neuron_gemv_kernel(
    const f32x4* __restrict__ values,   // [M][2] as f32x4
    const f32x4* __restrict__ weights,  // [U][16] as f32x4
    const int*   __restrict__ input_idx,
    const int*   __restrict__ weight_idx,
    f32x4*       __restrict__ out,      // [N][2] as f32x4
    int N, int T)                       // T = total threads (stride)
{
    int tid = blockIdx.x * blockDim.x + threadIdx.x;

    int  n[NPT];
    bool act[NPT];
#pragma unroll
    for (int k = 0; k < NPT; ++k) {
        n[k]   = tid + k * T;
        act[k] = n[k] < N;
    }

    // Phase 1: batch all index loads (coalesced, independent)
    int ii[NPT], wi[NPT];
#pragma unroll
    for (int k = 0; k < NPT; ++k) {
        ii[k] = act[k] ? input_idx[n[k]]  : 0;
        wi[k] = act[k] ? weight_idx[n[k]] : 0;
    }

    // Phase 2: batch all value-row gathers (8 independent 16B loads in flight)
    f32x4 x0[NPT], x1[NPT];
#pragma unroll
    for (int k = 0; k < NPT; ++k) {
        x0[k] = values[(size_t)ii[k] * 2 + 0];
        x1[k] = values[(size_t)ii[k] * 2 + 1];
    }

    // Phase 3: per-neuron weight load (L2-hot, 256 KB table) + FMA + store
#pragma unroll
    for (int k = 0; k < NPT; ++k) {
        if (!act[k]) continue;
        const f32x4* w = weights + (size_t)wi[k] * 16;
        float y[8];
#pragma unroll
        for (int r = 0; r < 8; ++r) {
            f32x4 w0 = w[r * 2 + 0];
            f32x4 w1 = w[r * 2 + 1];
            y[r] = w0.x * x0[k].x + w0.y * x0[k].y + w0.z * x0[k].z + w0.w * x0[k].w
                 + w1.x * x1[k].x + w1.y * x1[k].y + w1.z * x1[k].z + w1.w * x1[k].w;
        }
        f32x4 o0 = { y[0], y[1], y[2], y[3] };
        f32x4 o1 = { y[4], y[5], y[6], y[7] };
        // Non-temporal: don't let the 62.5 MB output stream evict L2-hot weights.
        __builtin_nontemporal_store(o0, &out[(size_t)n[k] * 2 + 0]);
        __builtin_nontemporal_store(o1, &out[(size_t)n[k] * 2 + 1]);
    }
}

extern "C" void kernel_launch(void* const* d_in, const int* in_sizes, int n_in,
                              void* d_out, int out_size, void* d_ws, size_t ws_size,
                              hipStream_t stream) {
    const f32x4* values  = (const f32x4*)d_in[0];
    const f32x4* weights = (const f32x4*)d_in[1];
    const int*   iidx    = (const int*)d_in[2];
    const int*   widx    = (const int*)d_in[3];
    f32x4*       out     = (f32x4*)d_out;

    int N = in_sizes[2];  // input_idx element count

    const int block = 256;
    const int grid  = (N + block * NPT - 1) / (block * NPT);
    const int T     = grid * block;
    neuron_gemv_kernel<<<grid, block, 0, stream>>>(values, weights, iidx, widx, out, N, T);
}

// Round 4
// 74.070 us; speedup vs baseline: 1.1921x; 1.1921x over previous
//
#include <hip/hip_runtime.h>

// y[n][r] = sum_c weights[weight_idx[n]][r][c] * values[input_idx[n]][c]
// N=2M, M=2M, U=1024, R=C=8, f32.
// Weights staged into LDS as f16 (1024 mats x 64 f16 = 128 KB) so the only
// VMEM traffic in the main loop is idx loads + the irreducible random value
// gather + coalesced output stores. Weight reads become ds_read_b128.

typedef float f32x4 __attribute__((ext_vector_type(4)));
typedef unsigned int u32;
typedef u32 u32x4 __attribute__((ext_vector_type(4)));
typedef __fp16 f16x2 __attribute__((ext_vector_type(2)));

#define NPT   2
#define BLOCK 1024
#define U_MATS 1024

union HU { u32 u; f16x2 h; };

__global__ __launch_bounds__(BLOCK) void neuron_gemv_kernel(
    const f32x4* __restrict__ values,   // [M][2] as f32x4
    const f32x4* __restrict__ weights,  // [U][16] as f32x4
    const int*   __restrict__ input_idx,
    const int*   __restrict__ weight_idx,
    f32x4*       __restrict__ out,      // [N][2] as f32x4
    int N, int T)
{
    // f16 weight table: matrix u, row r -> 16 B at wlds[u*32 + r*4 ..]
    __shared__ u32 wlds[U_MATS * 32];   // 128 KB

    // Stage: coalesced f32x4 reads of the L2-hot table, convert to f16.
    for (int g = threadIdx.x; g < U_MATS * 16; g += BLOCK) {
        f32x4 v = weights[g];
        HU a, b;
        a.h = f16x2{(__fp16)v.x, (__fp16)v.y};
        b.h = f16x2{(__fp16)v.z, (__fp16)v.w};
        wlds[g * 2 + 0] = a.u;
        wlds[g * 2 + 1] = b.u;
    }
    __syncthreads();

    const u32x4* wl4 = (const u32x4*)wlds;  // 8 u32x4 per matrix (one per row)

    int tid = blockIdx.x * BLOCK + threadIdx.x;

    int  n[NPT];
    bool act[NPT];
#pragma unroll
    for (int k = 0; k < NPT; ++k) {
        n[k]   = tid + k * T;
        act[k] = n[k] < N;
    }

    // Batch idx loads (coalesced, independent)
    int ii[NPT], wi[NPT];
#pragma unroll
    for (int k = 0; k < NPT; ++k) {
        ii[k] = act[k] ? input_idx[n[k]]  : 0;
        wi[k] = act[k] ? weight_idx[n[k]] : 0;
    }

    // Batch value-row gathers (independent 16 B loads in flight)
    f32x4 x0[NPT], x1[NPT];
#pragma unroll
    for (int k = 0; k < NPT; ++k) {
        x0[k] = values[(size_t)ii[k] * 2 + 0];
        x1[k] = values[(size_t)ii[k] * 2 + 1];
    }

    // Compute from LDS weights + store
#pragma unroll
    for (int k = 0; k < NPT; ++k) {
        if (!act[k]) continue;
        int base = wi[k] * 8;
        float y[8];
#pragma unroll
        for (int r = 0; r < 8; ++r) {
            u32x4 wr = wl4[base + r];   // ds_read_b128: one f16 weight row
            HU p0, p1, p2, p3;
            p0.u = wr.x; p1.u = wr.y; p2.u = wr.z; p3.u = wr.w;
            y[r] = (float)p0.h.x * x0[k].x + (float)p0.h.y * x0[k].y
                 + (float)p1.h.x * x0[k].z + (float)p1.h.y * x0[k].w
                 + (float)p2.h.x * x1[k].x + (float)p2.h.y * x1[k].y
                 + (float)p3.h.x * x1[k].z + (float)p3.h.y * x1[k].w;
        }
        f32x4 o0 = { y[0], y[1], y[2], y[3] };
        f32x4 o1 = { y[4], y[5], y[6], y[7] };
        out[(size_t)n[k] * 2 + 0] = o0;
        out[(size_t)n[k] * 2 + 1] = o1;
    }
}

extern "C" void kernel_launch(void* const* d_in, const int* in_sizes, int n_in,
                              void* d_out, int out_size, void* d_ws, size_t ws_size,
                              hipStream_t stream) {
    const f32x4* values  = (const f32x4*)d_in[0];
    const f32x4* weights = (const f32x4*)d_in[1];
    const int*   iidx    = (const int*)d_in[2];
    const int*   widx    = (const int*)d_in[3];
    f32x4*       out     = (f32x4*)d_out;

    int N = in_sizes[2];  // input_idx element count

    const int grid = (N + BLOCK * NPT - 1) / (BLOCK * NPT);
    const int T    = grid * BLOCK;
    neuron_gemv_kernel<<<grid, BLOCK, 0, stream>>>(values, weights, iidx, widx, out, N, T);
}

// Round 5
// 73.277 us; speedup vs baseline: 1.2050x; 1.0108x over previous
//
#include <hip/hip_runtime.h>

// y[n][r] = sum_c weights[weight_idx[n]][r][c] * values[input_idx[n]][c]
// N=2M, M=2M, U=1024, R=C=8, f32.
// Weights staged into LDS as f16 (128 KB). Row-rotation swizzle: matrix u's
// row r lives at ((r+u)&7) inside u's 32-u32 slot, so concurrent lanes with
// random u spread ds_read_b128 across all 32 banks (was: every matrix base
// bank-0-aligned -> all 64 lanes on one 4-bank group -> 8.5M conflict cycles).

typedef float f32x4 __attribute__((ext_vector_type(4)));
typedef unsigned int u32;
typedef u32 u32x4 __attribute__((ext_vector_type(4)));
typedef __fp16 f16x2 __attribute__((ext_vector_type(2)));

#define NPT   2
#define BLOCK 1024
#define U_MATS 1024

union HU { u32 u; f16x2 h; };

__global__ __launch_bounds__(BLOCK) void neuron_gemv_kernel(
    const f32x4* __restrict__ values,   // [M][2] as f32x4
    const f32x4* __restrict__ weights,  // [U][16] as f32x4
    const int*   __restrict__ input_idx,
    const int*   __restrict__ weight_idx,
    f32x4*       __restrict__ out,      // [N][2] as f32x4
    int N, int T)
{
    // f16 weight table, row-rotated: matrix u, logical row r ->
    // u32 offset u*32 + ((r+u)&7)*4
    __shared__ u32 wlds[U_MATS * 32];   // 128 KB

    // Stage: coalesced f32x4 reads of the L2-hot table, convert to f16,
    // write to swizzled slot.
    for (int g = threadIdx.x; g < U_MATS * 16; g += BLOCK) {
        f32x4 v = weights[g];
        int u = g >> 4;
        int e = g & 15;
        int r = e >> 1;       // logical row
        int h = e & 1;        // half of row (2 u32 per half)
        int dst = u * 32 + (((r + u) & 7) << 2) + h * 2;
        HU a, b;
        a.h = f16x2{(__fp16)v.x, (__fp16)v.y};
        b.h = f16x2{(__fp16)v.z, (__fp16)v.w};
        wlds[dst + 0] = a.u;
        wlds[dst + 1] = b.u;
    }
    __syncthreads();

    const u32x4* wl4 = (const u32x4*)wlds;  // row r of matrix u at wl4[u*8 + ((r+u)&7)]

    int tid = blockIdx.x * BLOCK + threadIdx.x;

    int  n[NPT];
    bool act[NPT];
#pragma unroll
    for (int k = 0; k < NPT; ++k) {
        n[k]   = tid + k * T;
        act[k] = n[k] < N;
    }

    // Batch idx loads (coalesced, independent)
    int ii[NPT], wi[NPT];
#pragma unroll
    for (int k = 0; k < NPT; ++k) {
        ii[k] = act[k] ? input_idx[n[k]]  : 0;
        wi[k] = act[k] ? weight_idx[n[k]] : 0;
    }

    // Batch value-row gathers (independent 16 B loads in flight)
    f32x4 x0[NPT], x1[NPT];
#pragma unroll
    for (int k = 0; k < NPT; ++k) {
        x0[k] = values[(size_t)ii[k] * 2 + 0];
        x1[k] = values[(size_t)ii[k] * 2 + 1];
    }

    // Compute from LDS weights + store
#pragma unroll
    for (int k = 0; k < NPT; ++k) {
        if (!act[k]) continue;
        int base = wi[k] * 8;
        int rot  = wi[k] & 7;
        float y[8];
#pragma unroll
        for (int r = 0; r < 8; ++r) {
            u32x4 wr = wl4[base + ((r + rot) & 7)];  // swizzled ds_read_b128
            HU p0, p1, p2, p3;
            p0.u = wr.x; p1.u = wr.y; p2.u = wr.z; p3.u = wr.w;
            y[r] = (float)p0.h.x * x0[k].x + (float)p0.h.y * x0[k].y
                 + (float)p1.h.x * x0[k].z + (float)p1.h.y * x0[k].w
                 + (float)p2.h.x * x1[k].x + (float)p2.h.y * x1[k].y
                 + (float)p3.h.x * x1[k].z + (float)p3.h.y * x1[k].w;
        }
        f32x4 o0 = { y[0], y[1], y[2], y[3] };
        f32x4 o1 = { y[4], y[5], y[6], y[7] };
        out[(size_t)n[k] * 2 + 0] = o0;
        out[(size_t)n[k] * 2 + 1] = o1;
    }
}

extern "C" void kernel_launch(void* const* d_in, const int* in_sizes, int n_in,
                              void* d_out, int out_size, void* d_ws, size_t ws_size,
                              hipStream_t stream) {
    const f32x4* values  = (const f32x4*)d_in[0];
    const f32x4* weights = (const f32x4*)d_in[1];
    const int*   iidx    = (const int*)d_in[2];
    const int*   widx    = (const int*)d_in[3];
    f32x4*       out     = (f32x4*)d_out;

    int N = in_sizes[2];  // input_idx element count

    const int grid = (N + BLOCK * NPT - 1) / (BLOCK * NPT);
    const int T    = grid * BLOCK;
    neuron_gemv_kernel<<<grid, BLOCK, 0, stream>>>(values, weights, iidx, widx, out, N, T);
}

// Round 6
// 58.967 us; speedup vs baseline: 1.4975x; 1.2427x over previous
//
#include <hip/hip_runtime.h>

// y[n][r] = sum_c weights[weight_idx[n]][r][c] * values[input_idx[n]][c]
// N=2M, M=2M, U=1024, R=C=8, f32.
// Persistent blocks: grid=256 (1 block/CU via 128KB LDS), weights staged to
// LDS as f16 ONCE, then grid-stride NPT=4 batches with prefetched indices so
// the idx->gather dependency is paid once, not per batch.

typedef float f32x4 __attribute__((ext_vector_type(4)));
typedef unsigned int u32;
typedef u32 u32x4 __attribute__((ext_vector_type(4)));
typedef __fp16 f16x2 __attribute__((ext_vector_type(2)));

#define NPT    4
#define BLOCK  1024
#define GRID   256
#define U_MATS 1024

union HU { u32 u; f16x2 h; };

__global__ __launch_bounds__(BLOCK) void neuron_gemv_kernel(
    const f32x4* __restrict__ values,   // [M][2] as f32x4
    const f32x4* __restrict__ weights,  // [U][16] as f32x4
    const int*   __restrict__ input_idx,
    const int*   __restrict__ weight_idx,
    f32x4*       __restrict__ out,      // [N][2] as f32x4
    int N)
{
    // f16 weight table, row-rotated swizzle: matrix u, logical row r ->
    // u32 offset u*32 + ((r+u)&7)*4  (spreads divergent ds_read_b128 over banks)
    __shared__ u32 wlds[U_MATS * 32];   // 128 KB -> 1 block/CU

    for (int g = threadIdx.x; g < U_MATS * 16; g += BLOCK) {
        f32x4 v = weights[g];
        int u = g >> 4;
        int e = g & 15;
        int r = e >> 1;
        int h = e & 1;
        int dst = u * 32 + (((r + u) & 7) << 2) + h * 2;
        HU a, b;
        a.h = f16x2{(__fp16)v.x, (__fp16)v.y};
        b.h = f16x2{(__fp16)v.z, (__fp16)v.w};
        wlds[dst + 0] = a.u;
        wlds[dst + 1] = b.u;
    }
    __syncthreads();

    const u32x4* wl4 = (const u32x4*)wlds;  // row r of mat u at wl4[u*8 + ((r+u)&7)]

    const int  T   = GRID * BLOCK;          // 262144 threads
    const int  tid = blockIdx.x * BLOCK + threadIdx.x;

    int ii[NPT], wi[NPT], iin[NPT], win[NPT];

    // Prologue: indices for first batch
    long base = tid;
#pragma unroll
    for (int j = 0; j < NPT; ++j) {
        long n  = base + (long)j * T;
        int  nc = (n < N) ? (int)n : 0;
        ii[j] = input_idx[nc];
        wi[j] = weight_idx[nc];
    }

    while (base < N) {
        long nextbase = base + (long)T * NPT;

        // Issue all gathers for current batch (independent, fill vmcnt queue)
        f32x4 x0[NPT], x1[NPT];
#pragma unroll
        for (int j = 0; j < NPT; ++j) {
            x0[j] = values[(size_t)ii[j] * 2 + 0];
            x1[j] = values[(size_t)ii[j] * 2 + 1];
        }

        // Prefetch next batch's indices BEFORE consuming gathers:
        // their latency hides under this batch's compute.
        if (nextbase < N) {
#pragma unroll
            for (int j = 0; j < NPT; ++j) {
                long n  = nextbase + (long)j * T;
                int  nc = (n < N) ? (int)n : 0;
                iin[j] = input_idx[nc];
                win[j] = weight_idx[nc];
            }
        }

        // Compute from LDS weights + store
#pragma unroll
        for (int j = 0; j < NPT; ++j) {
            long n = base + (long)j * T;
            if (n >= N) continue;
            int b   = wi[j] * 8;
            int rot = wi[j] & 7;
            float y[8];
#pragma unroll
            for (int r = 0; r < 8; ++r) {
                u32x4 wr = wl4[b + ((r + rot) & 7)];
                HU p0, p1, p2, p3;
                p0.u = wr.x; p1.u = wr.y; p2.u = wr.z; p3.u = wr.w;
                y[r] = (float)p0.h.x * x0[j].x + (float)p0.h.y * x0[j].y
                     + (float)p1.h.x * x0[j].z + (float)p1.h.y * x0[j].w
                     + (float)p2.h.x * x1[j].x + (float)p2.h.y * x1[j].y
                     + (float)p3.h.x * x1[j].z + (float)p3.h.y * x1[j].w;
            }
            f32x4 o0 = { y[0], y[1], y[2], y[3] };
            f32x4 o1 = { y[4], y[5], y[6], y[7] };
            out[(size_t)n * 2 + 0] = o0;
            out[(size_t)n * 2 + 1] = o1;
        }

        base = nextbase;
#pragma unroll
        for (int j = 0; j < NPT; ++j) { ii[j] = iin[j]; wi[j] = win[j]; }
    }
}

extern "C" void kernel_launch(void* const* d_in, const int* in_sizes, int n_in,
                              void* d_out, int out_size, void* d_ws, size_t ws_size,
                              hipStream_t stream) {
    const f32x4* values  = (const f32x4*)d_in[0];
    const f32x4* weights = (const f32x4*)d_in[1];
    const int*   iidx    = (const int*)d_in[2];
    const int*   widx    = (const int*)d_in[3];
    f32x4*       out     = (f32x4*)d_out;

    int N = in_sizes[2];  // input_idx element count

    neuron_gemv_kernel<<<GRID, BLOCK, 0, stream>>>(values, weights, iidx, widx, out, N);
}